// Round 8
// baseline (1016.765 us; speedup 1.0000x reference)
//
#include <hip/hip_runtime.h>
#include <hip/hip_fp16.h>

// Problem constants (from reference)
#define C_REL 5
#define NN    50000
#define EE    800000
#define D_IN  128
#define D_H   128
#define D_OUT 64

static constexpr int CN = C_REL * NN;            // 250000
static constexpr int CE = C_REL * EE;            // 4000000
static constexpr int SCAN_B = (NN + 255) / 256;  // 196 blocks per relation
static constexpr int BLK_GEMM_REL = (NN + 63) / 64;   // 782
static constexpr int GEMM_BLOCKS  = C_REL * BLK_GEMM_REL; // 3910
static constexpr int HIST_BLOCKS  = 4096;
static constexpr int FUSED_GRID   = 2 * HIST_BLOCKS;      // 8192, 1:1 interleave
static constexpr int FILL0_BLOCKS = 1024;

static constexpr int RSZ  = 12500;   // src-range size (NN/4): 3.2MB fp16 slice @F=128
static constexpr int NPW  = 8;       // nodes per wave in agg (50000 = 6250 waves * 8)
static constexpr int A_BLOCKS  = 1568;               // agg blocks per relation (6272 waves)
static constexpr int AF_FILLB  = 448;                // staggered fill blocks
static constexpr int AF_GRID   = A_BLOCKS + AF_FILLB; // 2016 (~all-resident)

static constexpr float FIX16     = 65536.0f;
static constexpr float FIX16_INV = 1.0f / 65536.0f;

__device__ inline unsigned pack2h(float a, float b) {
  __half2 h = __floats2half2_rn(a, b);
  return *reinterpret_cast<unsigned*>(&h);
}

// ---------------------------------------------------------------------------
// Prep: 64-bit packed histogram atomic: [cnt_r3:10|cnt_r2:10|cnt_r1:10|cnt_r0:10|wsum_fix16:24]
// Per-(node,src-range) counts; atomic return gives rank within (node,range).
// Max per-range degree ~Poisson(4) << 1023; wsum <= 64*2^16 < 2^24. Safe.
// ---------------------------------------------------------------------------

__global__ __launch_bounds__(256) void init_kernel(unsigned long long* packed) {
  int i = blockIdx.x * 256 + threadIdx.x;
  if (i < CN) packed[i] = 0ULL;
}

__device__ inline void hist_body(int bid, int nblocks,
                                 const int* __restrict__ ei,
                                 const float* __restrict__ ew,
                                 unsigned long long* packed,
                                 int* __restrict__ pos) {
  int stride = nblocks * 256;
  for (int idx = bid * 256 + threadIdx.x; idx < CE; idx += stride) {
    int c = idx / EE, e = idx - c * EE;
    int s = ei[(c * 2 + 0) * EE + e];
    int d = ei[(c * 2 + 1) * EE + e];
    float w = ew[idx];
    unsigned wfix = (unsigned)(w * FIX16 + 0.5f);       // <= 65536
    int r = s / RSZ;                                     // 0..3
    int sh = 24 + 10 * r;
    unsigned long long old =
        atomicAdd(&packed[c * NN + d], (unsigned long long)wfix | (1ULL << sh));
    pos[idx] = (int)((old >> sh) & 1023ULL);             // rank within (node,range)
  }
}

// scan_a: per-256-block inclusive scan of total counts; dis = rsqrt(1+wsum);
// subb = packed range sub-bases (s1,s2,s3,total) as 4x16b.
__global__ __launch_bounds__(256) void scan_a_kernel(const unsigned long long* __restrict__ packed,
                                                     int* rowptr, int* bsum,
                                                     float* __restrict__ dis,
                                                     uint2* __restrict__ subb) {
  int c = blockIdx.x / SCAN_B;
  int b = blockIdx.x - c * SCAN_B;
  int tid = threadIdx.x;
  int i = b * 256 + tid;
  int val = 0;
  if (i < NN) {
    unsigned long long p = packed[c * NN + i];
    unsigned c0 = (unsigned)(p >> 24) & 1023u;
    unsigned c1 = (unsigned)(p >> 34) & 1023u;
    unsigned c2 = (unsigned)(p >> 44) & 1023u;
    unsigned c3 = (unsigned)(p >> 54) & 1023u;
    val = (int)(c0 + c1 + c2 + c3);
    dis[c * NN + i] = rsqrtf(1.0f + (float)(unsigned)(p & 0xFFFFFFu) * FIX16_INV);
    unsigned s1 = c0, s2 = c0 + c1, s3 = c0 + c1 + c2;
    subb[c * NN + i] = make_uint2(s1 | (s2 << 16), s3 | ((unsigned)val << 16));
  }
  __shared__ int sh[256];
  sh[tid] = val;
  __syncthreads();
  for (int off = 1; off < 256; off <<= 1) {
    int t = (tid >= off) ? sh[tid - off] : 0;
    __syncthreads();
    sh[tid] += t;
    __syncthreads();
  }
  if (i < NN) rowptr[c * (NN + 1) + i + 1] = sh[tid];
  if (tid == 255) bsum[c * 256 + b] = sh[255];
}

// scan_c: add prefix of bsum[0..b) (each wave redundantly reduces <=196 vals).
__global__ __launch_bounds__(256) void scan_c_kernel(int* rowptr, const int* __restrict__ bsum) {
  int c = blockIdx.x / SCAN_B;
  int b = blockIdx.x - c * SCAN_B;
  int tid = threadIdx.x;
  int lane = tid & 63;
  int acc = 0;
  for (int t = lane; t < b; t += 64) acc += bsum[c * 256 + t];
#pragma unroll
  for (int o = 1; o < 64; o <<= 1) acc += __shfl_xor(acc, o, 64);
  int i = b * 256 + tid;
  if (i < NN) rowptr[c * (NN + 1) + i + 1] += acc;
  if (i == 0) rowptr[c * (NN + 1)] = 0;
}

// fill: atomic-free; slot = rowptr[d] + subbase[range(s)] + rank.
// Entry = src:16 | half(norm):16. Edges grouped by src-range within each node.
__device__ inline void fill_rel_body(int c, int bid, int nblocks,
                                     const int* __restrict__ ei,
                                     const float* __restrict__ ew,
                                     const float* __restrict__ dis,
                                     const int* __restrict__ rowptr,
                                     const uint2* __restrict__ subb,
                                     const int* __restrict__ pos,
                                     unsigned* __restrict__ csr) {
  int stride = nblocks * 256;
  const int* srcp = ei + (size_t)(c * 2) * EE;
  const int* dstp = srcp + EE;
  const float* ewc = ew + (size_t)c * EE;
  const int* posc = pos + (size_t)c * EE;
  const float* disc = dis + c * NN;
  const int* rpc = rowptr + c * (NN + 1);
  const uint2* sbc = subb + (size_t)c * NN;
  unsigned* csrc = csr + (size_t)c * EE;
  for (int e = bid * 256 + threadIdx.x; e < EE; e += stride) {
    int s = srcp[e];
    int d = dstp[e];
    float nrm = disc[s] * ewc[e] * disc[d];
    int r = s / RSZ;
    uint2 sb = sbc[d];
    unsigned base = (r == 0) ? 0u
                  : (r == 1) ? (sb.x & 0xffffu)
                  : (r == 2) ? (sb.x >> 16)
                             : (sb.y & 0xffffu);
    int slot = rpc[d] + (int)base + posc[e];
    csrc[slot] = (unsigned)s | ((unsigned)__half_as_ushort(__float2half_rn(nrm)) << 16);
  }
}

__global__ __launch_bounds__(256) void fill0_kernel(const int* __restrict__ ei,
                                                    const float* __restrict__ ew,
                                                    const float* __restrict__ dis,
                                                    const int* __restrict__ rowptr,
                                                    const uint2* __restrict__ subb,
                                                    const int* __restrict__ pos,
                                                    unsigned* __restrict__ csr) {
  fill_rel_body(0, blockIdx.x, FILL0_BLOCKS, ei, ew, dis, rowptr, subb, pos, csr);
}

// ---------------------------------------------------------------------------
// GEMM body: C[c] = A[c] @ B[c], fp32 math, fp16 row-major output.
// B staged per-K-chunk -> LDS ~25KB -> 6 blocks/CU.
// ---------------------------------------------------------------------------

template <int NC, bool AHALF>
__device__ inline void gemm_body(int bid, const void* __restrict__ Av,
                                 const float* __restrict__ B,
                                 __half* __restrict__ Cout) {
  constexpr int K = 128;
  constexpr int KC = 32;
  constexpr int CPT = NC / 32;
  __shared__ float Bs[KC * NC];
  __shared__ float As[64][KC + 4];

  int c  = bid / BLK_GEMM_REL;
  int bl = bid - c * BLK_GEMM_REL;
  const float* Bc = B + (size_t)c * K * NC;
  __half* Cc = Cout + (size_t)c * NN * NC;

  int tid = threadIdx.x;
  int tx = tid & 31;
  int ty = tid >> 5;
  int rowBase = bl * 64;

  float acc[8][CPT];
#pragma unroll
  for (int i = 0; i < 8; ++i)
#pragma unroll
    for (int j = 0; j < CPT; ++j) acc[i][j] = 0.f;

  for (int kc = 0; kc < K; kc += KC) {
    __syncthreads();
    {
      const float4* B4 = (const float4*)(Bc + (size_t)kc * NC);
      float4* Bs4 = (float4*)Bs;
#pragma unroll
      for (int i = tid; i < KC * NC / 4; i += 256) Bs4[i] = B4[i];
    }
    if constexpr (AHALF) {
      const __half* Ac = (const __half*)Av + (size_t)c * NN * K;
      int lr = tid >> 2;
      int lc = (tid & 3) * 8;
      int gr = rowBase + lr;
      uint4 v = make_uint4(0u, 0u, 0u, 0u);
      if (gr < NN) v = *(const uint4*)&Ac[(size_t)gr * K + kc + lc];
      const __half2* hp = (const __half2*)&v;
#pragma unroll
      for (int j = 0; j < 4; ++j) {
        float2 f = __half22float2(hp[j]);
        As[lr][lc + 2 * j]     = f.x;
        As[lr][lc + 2 * j + 1] = f.y;
      }
    } else {
      const float* Ac = (const float*)Av + (size_t)c * NN * K;
      int lr = tid >> 3;
      int lc = (tid & 7) * 4;
#pragma unroll
      for (int rr = 0; rr < 64; rr += 32) {
        int r = lr + rr;
        int gr = rowBase + r;
        float4 v = make_float4(0.f, 0.f, 0.f, 0.f);
        if (gr < NN) v = *(const float4*)&Ac[(size_t)gr * K + kc + lc];
        *(float4*)&As[r][lc] = v;
      }
    }
    __syncthreads();

#pragma unroll
    for (int kk = 0; kk < KC; kk += 4) {
      float4 av[8];
#pragma unroll
      for (int i = 0; i < 8; ++i) av[i] = *(const float4*)&As[ty * 8 + i][kk];
#pragma unroll
      for (int u = 0; u < 4; ++u) {
        int k = kk + u;
        if constexpr (CPT == 4) {
          float4 bv = *(const float4*)&Bs[k * NC + tx * 4];
#pragma unroll
          for (int i = 0; i < 8; ++i) {
            float a = ((const float*)&av[i])[u];
            acc[i][0] += a * bv.x;
            acc[i][1] += a * bv.y;
            acc[i][2] += a * bv.z;
            acc[i][3] += a * bv.w;
          }
        } else {
          float2 bv = *(const float2*)&Bs[k * NC + tx * 2];
#pragma unroll
          for (int i = 0; i < 8; ++i) {
            float a = ((const float*)&av[i])[u];
            acc[i][0] += a * bv.x;
            acc[i][1] += a * bv.y;
          }
        }
      }
    }
  }

#pragma unroll
  for (int i = 0; i < 8; ++i) {
    int gr = rowBase + ty * 8 + i;
    if (gr >= NN) continue;
    if constexpr (CPT == 4) {
      unsigned lo = pack2h(acc[i][0], acc[i][1]);
      unsigned hi = pack2h(acc[i][2], acc[i][3]);
      *(uint2*)&Cc[(size_t)gr * NC + tx * 4] = make_uint2(lo, hi);
    } else {
      *(unsigned*)&Cc[(size_t)gr * NC + tx * 2] = pack2h(acc[i][0], acc[i][1]);
    }
  }
}

// Fused: hist (atomic-bound) || gemm1 (VALU-bound) - fully independent.
__global__ __launch_bounds__(256) void fused_hist_gemm1_kernel(
    const float* __restrict__ x, const float* __restrict__ W1, __half* __restrict__ h1,
    const int* __restrict__ ei, const float* __restrict__ ew,
    unsigned long long* packed, int* __restrict__ pos) {
  int id = blockIdx.x;
  if (id & 1) {
    hist_body(id >> 1, HIST_BLOCKS, ei, ew, packed, pos);
  } else {
    int gid = id >> 1;
    if (gid < GEMM_BLOCKS) gemm_body<D_H, false>(gid, x, W1, h1);
  }
}

__global__ __launch_bounds__(256) void gemm2_kernel(const __half* __restrict__ A,
                                                    const float* __restrict__ B,
                                                    __half* __restrict__ Cout) {
  gemm_body<D_OUT, true>(blockIdx.x, A, B, Cout);
}

// ---------------------------------------------------------------------------
// Pass-phased aggregation: wave owns 8 contiguous nodes, accumulators in
// registers; outer loop over 4 src-ranges so co-resident waves gather from
// the same 3.2MB (F=128) / 1.6MB (F=64) slice -> per-XCD L2 resident.
// ---------------------------------------------------------------------------

__device__ inline void agg1_body(int c, int wid, const __half2* __restrict__ h,
                                 const int* __restrict__ rowptr,
                                 const uint2* __restrict__ subb,
                                 const unsigned* __restrict__ csr,
                                 const float* __restrict__ dis,
                                 const float* __restrict__ bias,
                                 __half* __restrict__ out) {
  int nbase = wid * NPW;
  if (nbase >= NN) return;                       // 50000 = 6250*8, full waves only
  int lane = threadIdx.x & 63;
  const __half2* hc = h + (size_t)c * (NN * 64);
  const unsigned* csrc = csr + (size_t)c * EE;
  const int* rpc = rowptr + c * (NN + 1);
  const uint2* sbc = subb + (size_t)c * NN;

  float a0[NPW], a1[NPW];
  int beg[NPW];
  unsigned sbx[NPW], sby[NPW];
#pragma unroll
  for (int i = 0; i < NPW; ++i) {
    a0[i] = 0.f; a1[i] = 0.f;
    beg[i] = rpc[nbase + i];
    uint2 t = sbc[nbase + i];
    sbx[i] = t.x; sby[i] = t.y;
  }
#pragma unroll
  for (int p = 0; p < 4; ++p) {
#pragma unroll
    for (int i = 0; i < NPW; ++i) {
      unsigned lo = (p == 0) ? 0u
                  : (p == 1) ? (sbx[i] & 0xffffu)
                  : (p == 2) ? (sbx[i] >> 16)
                             : (sby[i] & 0xffffu);
      unsigned hi = (p == 0) ? (sbx[i] & 0xffffu)
                  : (p == 1) ? (sbx[i] >> 16)
                  : (p == 2) ? (sby[i] & 0xffffu)
                             : (sby[i] >> 16);
      int ib = beg[i] + (int)lo;
      int ie = beg[i] + (int)hi;
      for (int idx = ib; idx < ie; ++idx) {
        unsigned e = csrc[idx];
        float2 v = __half22float2(hc[(e & 0xffffu) * 64u + (unsigned)lane]);
        float nm = __half2float(__ushort_as_half((unsigned short)(e >> 16)));
        a0[i] += nm * v.x;
        a1[i] += nm * v.y;
      }
    }
  }
#pragma unroll
  for (int i = 0; i < NPW; ++i) {
    int node = nbase + i;
    float dn = dis[c * NN + node];
    float sn = dn * dn;
    float2 hv = __half22float2(hc[(unsigned)node * 64u + (unsigned)lane]);
    int f = lane * 2;
    float r0 = a0[i] + sn * hv.x + bias[c * 128 + f];
    float r1 = a1[i] + sn * hv.y + bias[c * 128 + f + 1];
    ((unsigned*)out)[((size_t)c * NN + node) * 64 + lane] =
        pack2h(fmaxf(r0, 0.f), fmaxf(r1, 0.f));
  }
}

// Fused: agg1(c) [A_BLOCKS] || fill(c+1) [AF_FILLB].
__global__ __launch_bounds__(256) void fused_agg1_fill_kernel(
    int c, const __half2* __restrict__ h, const int* __restrict__ rowptr,
    const uint2* __restrict__ subb, const unsigned* __restrict__ csr,
    const float* __restrict__ dis, const float* __restrict__ bias,
    __half* __restrict__ out, const int* __restrict__ ei,
    const float* __restrict__ ew, const int* __restrict__ pos) {
  int bid = blockIdx.x;
  if (bid < A_BLOCKS) {
    int wid = bid * 4 + (threadIdx.x >> 6);
    agg1_body(c, wid, h, rowptr, subb, csr, dis, bias, out);
  } else if (c + 1 < C_REL) {
    fill_rel_body(c + 1, bid - A_BLOCKS, AF_FILLB, ei, ew, dis, rowptr, subb, pos,
                  (unsigned*)csr);
  }
}

// agg2: F=64, half-wave edge split within each range, shfl_xor(32) at epilogue.
__global__ __launch_bounds__(256) void agg2_kernel(const __half2* __restrict__ h,
                                                   const int* __restrict__ rowptr,
                                                   const uint2* __restrict__ subb,
                                                   const unsigned* __restrict__ csr,
                                                   const float* __restrict__ dis,
                                                   const float* __restrict__ bias,
                                                   float* __restrict__ out) {
  int c = blockIdx.x / A_BLOCKS;
  int bid = blockIdx.x - c * A_BLOCKS;
  int wid = bid * 4 + (threadIdx.x >> 6);
  int nbase = wid * NPW;
  if (nbase >= NN) return;
  int lane = threadIdx.x & 63;
  int hf = lane >> 5;
  int fl = lane & 31;
  const __half2* hc = h + (size_t)c * (NN * 32);
  const unsigned* csrc = csr + (size_t)c * EE;
  const int* rpc = rowptr + c * (NN + 1);
  const uint2* sbc = subb + (size_t)c * NN;

  float a0[NPW], a1[NPW];
  int beg[NPW];
  unsigned sbx[NPW], sby[NPW];
#pragma unroll
  for (int i = 0; i < NPW; ++i) {
    a0[i] = 0.f; a1[i] = 0.f;
    beg[i] = rpc[nbase + i];
    uint2 t = sbc[nbase + i];
    sbx[i] = t.x; sby[i] = t.y;
  }
#pragma unroll
  for (int p = 0; p < 4; ++p) {
#pragma unroll
    for (int i = 0; i < NPW; ++i) {
      unsigned lo = (p == 0) ? 0u
                  : (p == 1) ? (sbx[i] & 0xffffu)
                  : (p == 2) ? (sbx[i] >> 16)
                             : (sby[i] & 0xffffu);
      unsigned hi = (p == 0) ? (sbx[i] & 0xffffu)
                  : (p == 1) ? (sbx[i] >> 16)
                  : (p == 2) ? (sby[i] & 0xffffu)
                             : (sby[i] >> 16);
      int ie = beg[i] + (int)hi;
      for (int idx = beg[i] + (int)lo + hf; idx < ie; idx += 2) {
        unsigned e = csrc[idx];
        float2 v = __half22float2(hc[(e & 0xffffu) * 32u + (unsigned)fl]);
        float nm = __half2float(__ushort_as_half((unsigned short)(e >> 16)));
        a0[i] += nm * v.x;
        a1[i] += nm * v.y;
      }
    }
  }
#pragma unroll
  for (int i = 0; i < NPW; ++i) {
    a0[i] += __shfl_xor(a0[i], 32, 64);
    a1[i] += __shfl_xor(a1[i], 32, 64);
  }
  if (hf == 0) {
#pragma unroll
    for (int i = 0; i < NPW; ++i) {
      int node = nbase + i;
      float dn = dis[c * NN + node];
      float sn = dn * dn;
      float2 hv = __half22float2(hc[(unsigned)node * 32u + (unsigned)fl]);
      int f = fl * 2;
      float r0 = a0[i] + sn * hv.x + bias[c * 64 + f];
      float r1 = a1[i] + sn * hv.y + bias[c * 64 + f + 1];
      *(float2*)&out[((size_t)c * NN + node) * 64 + f] = make_float2(r0, r1);
    }
  }
}

// ---------------------------------------------------------------------------
// Host launcher
// ---------------------------------------------------------------------------

extern "C" void kernel_launch(void* const* d_in, const int* in_sizes, int n_in,
                              void* d_out, int out_size, void* d_ws, size_t ws_size,
                              hipStream_t stream) {
  const float* x  = (const float*)d_in[0];   // [C][N][128]
  const int*   ei = (const int*)d_in[1];     // [C][2][E]
  const float* ew = (const float*)d_in[2];   // [C][E]
  const float* W1 = (const float*)d_in[3];   // [C][128][128]
  const float* b1 = (const float*)d_in[4];   // [C][128]
  const float* W2 = (const float*)d_in[5];   // [C][128][64]
  const float* b2 = (const float*)d_in[6];   // [C][64]
  float* out = (float*)d_out;                // [C][N][64]

  char* ws = (char*)d_ws;
  size_t off = 0;
  auto alloc = [&](size_t bytes) {
    size_t cur = off;
    off += (bytes + 255) & ~(size_t)255;
    return cur;
  };
  unsigned long long* packed = (unsigned long long*)(ws + alloc((size_t)CN * 8));
  float*    dis    = (float*)   (ws + alloc((size_t)CN * 4));
  int*      rowptr = (int*)     (ws + alloc((size_t)C_REL * (NN + 1) * 4));
  int*      bsum   = (int*)     (ws + alloc((size_t)C_REL * 256 * 4));
  uint2*    subb   = (uint2*)   (ws + alloc((size_t)CN * 8));
  unsigned* csr    = (unsigned*)(ws + alloc((size_t)CE * 4));
  __half*   h1     = (__half*)  (ws + alloc((size_t)CN * D_H * 2));   // h1/h2 fp16
  __half*   agg1h  = (__half*)  (ws + alloc((size_t)CN * D_H * 2));   // relu out fp16
  // pos[CE] (16MB) lives in d_out (64MB): d_out written only by agg2 at the end;
  // last pos read is the staggered fill(4) inside the c=3 fused dispatch.
  int* pos = (int*)out;

  const int NB_CN = (CN + 255) / 256;

  init_kernel<<<NB_CN, 256, 0, stream>>>(packed);
  // hist (atomic-bound) overlapped with gemm1 (VALU-bound, independent).
  fused_hist_gemm1_kernel<<<FUSED_GRID, 256, 0, stream>>>(x, W1, h1, ei, ew, packed, pos);
  scan_a_kernel<<<C_REL * SCAN_B, 256, 0, stream>>>(packed, rowptr, bsum, dis, subb);
  scan_c_kernel<<<C_REL * SCAN_B, 256, 0, stream>>>(rowptr, bsum);
  fill0_kernel<<<FILL0_BLOCKS, 256, 0, stream>>>(ei, ew, dis, rowptr, subb, pos, csr);

  // agg1(c) pass-phased (L2-resident src-range slices) || fill(c+1).
  for (int c = 0; c < C_REL; ++c) {
    fused_agg1_fill_kernel<<<AF_GRID, 256, 0, stream>>>(
        c, (const __half2*)h1, rowptr, subb, csr, dis, b1, agg1h, ei, ew, pos);
  }
  gemm2_kernel<<<GEMM_BLOCKS, 256, 0, stream>>>(agg1h, W2, h1);
  agg2_kernel<<<C_REL * A_BLOCKS, 256, 0, stream>>>((const __half2*)h1, rowptr, subb,
                                                    csr, dis, b2, out);
}

// Round 9
// 883.836 us; speedup vs baseline: 1.1504x; 1.1504x over previous
//
#include <hip/hip_runtime.h>
#include <hip/hip_fp16.h>

// Problem constants (from reference)
#define C_REL 5
#define NN    50000
#define EE    800000
#define D_IN  128
#define D_H   128
#define D_OUT 64

static constexpr int CN = C_REL * NN;            // 250000
static constexpr int CE = C_REL * EE;            // 4000000
static constexpr int SCAN_B = (NN + 255) / 256;  // 196 blocks per relation
static constexpr int BLK_GEMM_REL = (NN + 63) / 64;   // 782
static constexpr int BLK_AGG_REL  = NN / 4;           // 12500
static constexpr int GEMM_BLOCKS  = C_REL * BLK_GEMM_REL; // 3910
static constexpr int HIST_BLOCKS  = 4096;
static constexpr int FUSED_GRID   = 2 * HIST_BLOCKS;      // 8192, 1:1 interleave
static constexpr int FILL0_BLOCKS = 1024;
// Pipelined dispatch: 22 roles per group of blocks (10 agg1 : 10 agg2 : 1 fill : 1 gemm2)
static constexpr int PIPE_GROUPS  = 1250;
static constexpr int PIPE_GRID    = PIPE_GROUPS * 22;     // 27500
static constexpr int FILLS_BLOCKS = 1250;

static constexpr float FIX16     = 65536.0f;
static constexpr float FIX16_INV = 1.0f / 65536.0f;

__device__ inline unsigned pack2h(float a, float b) {
  __half2 h = __floats2half2_rn(a, b);
  return *reinterpret_cast<unsigned*>(&h);
}

// ---------------------------------------------------------------------------
// Prep: 32-bit packed histogram atomic: [count:10 | wsum_fix16:22].
// Atomic return's count field = edge's rank within its dst bucket.
// ---------------------------------------------------------------------------

__global__ __launch_bounds__(256) void init_kernel(unsigned* packed) {
  int i = blockIdx.x * 256 + threadIdx.x;
  if (i < CN) packed[i] = 0u;
}

__device__ inline void hist_body(int bid, int nblocks,
                                 const int* __restrict__ ei,
                                 const float* __restrict__ ew,
                                 unsigned* packed,
                                 int* __restrict__ pos) {
  int stride = nblocks * 256;
  for (int idx = bid * 256 + threadIdx.x; idx < CE; idx += stride) {
    int c = idx / EE, e = idx - c * EE;
    int d = ei[(c * 2 + 1) * EE + e];
    float w = ew[idx];
    unsigned wfix = (unsigned)(w * FIX16 + 0.5f);       // <= 65536
    unsigned old = atomicAdd(&packed[c * NN + d], wfix | (1u << 22));
    pos[idx] = (int)(old >> 22);
  }
}

// scan_a: per-256-block inclusive scan of counts; also dis = rsqrt(1+wsum).
__global__ __launch_bounds__(256) void scan_a_kernel(const unsigned* __restrict__ packed,
                                                     int* rowptr, int* bsum,
                                                     float* __restrict__ dis) {
  int c = blockIdx.x / SCAN_B;
  int b = blockIdx.x - c * SCAN_B;
  int tid = threadIdx.x;
  int i = b * 256 + tid;
  int val = 0;
  if (i < NN) {
    unsigned p = packed[c * NN + i];
    val = (int)(p >> 22);
    dis[c * NN + i] = rsqrtf(1.0f + (float)(p & 0x3FFFFFu) * FIX16_INV);
  }
  __shared__ int sh[256];
  sh[tid] = val;
  __syncthreads();
  for (int off = 1; off < 256; off <<= 1) {
    int t = (tid >= off) ? sh[tid - off] : 0;
    __syncthreads();
    sh[tid] += t;
    __syncthreads();
  }
  if (i < NN) rowptr[c * (NN + 1) + i + 1] = sh[tid];
  if (tid == 255) bsum[c * 256 + b] = sh[255];
}

// scan_c: add prefix of bsum[0..b) (each wave redundantly reduces <=196 vals).
__global__ __launch_bounds__(256) void scan_c_kernel(int* rowptr, const int* __restrict__ bsum) {
  int c = blockIdx.x / SCAN_B;
  int b = blockIdx.x - c * SCAN_B;
  int tid = threadIdx.x;
  int lane = tid & 63;
  int acc = 0;
  for (int t = lane; t < b; t += 64) acc += bsum[c * 256 + t];
#pragma unroll
  for (int o = 1; o < 64; o <<= 1) acc += __shfl_xor(acc, o, 64);
  int i = b * 256 + tid;
  if (i < NN) rowptr[c * (NN + 1) + i + 1] += acc;
  if (i == 0) rowptr[c * (NN + 1)] = 0;
}

// fill body for one relation: atomic-free; entry = src:16 | half(norm):16.
__device__ inline void fill_rel_body(int c, int bid, int nblocks,
                                     const int* __restrict__ ei,
                                     const float* __restrict__ ew,
                                     const float* __restrict__ dis,
                                     const int* __restrict__ rowptr,
                                     const int* __restrict__ pos,
                                     unsigned* __restrict__ csr) {
  int stride = nblocks * 256;
  const int* srcp = ei + (size_t)(c * 2) * EE;
  const int* dstp = srcp + EE;
  const float* ewc = ew + (size_t)c * EE;
  const int* posc = pos + (size_t)c * EE;
  const float* disc = dis + c * NN;
  const int* rpc = rowptr + c * (NN + 1);
  unsigned* csrc = csr + (size_t)c * EE;
  for (int e = bid * 256 + threadIdx.x; e < EE; e += stride) {
    int s = srcp[e];
    int d = dstp[e];
    float nrm = disc[s] * ewc[e] * disc[d];
    unsigned ent = (unsigned)s | ((unsigned)__half_as_ushort(__float2half_rn(nrm)) << 16);
    csrc[rpc[d] + posc[e]] = ent;
  }
}

__global__ __launch_bounds__(256) void fill0_kernel(const int* __restrict__ ei,
                                                    const float* __restrict__ ew,
                                                    const float* __restrict__ dis,
                                                    const int* __restrict__ rowptr,
                                                    const int* __restrict__ pos,
                                                    unsigned* __restrict__ csr) {
  fill_rel_body(0, blockIdx.x, FILL0_BLOCKS, ei, ew, dis, rowptr, pos, csr);
}

// ---------------------------------------------------------------------------
// GEMM body: C[c] = A[c] @ B[c], fp32 math, fp16 row-major output.
// B staged per-K-chunk -> LDS ~25KB -> 6 blocks/CU.
// ---------------------------------------------------------------------------

template <int NC, bool AHALF>
__device__ inline void gemm_body(int bid, const void* __restrict__ Av,
                                 const float* __restrict__ B,
                                 __half* __restrict__ Cout) {
  constexpr int K = 128;
  constexpr int KC = 32;
  constexpr int CPT = NC / 32;
  __shared__ float Bs[KC * NC];
  __shared__ float As[64][KC + 4];

  int c  = bid / BLK_GEMM_REL;
  int bl = bid - c * BLK_GEMM_REL;
  const float* Bc = B + (size_t)c * K * NC;
  __half* Cc = Cout + (size_t)c * NN * NC;

  int tid = threadIdx.x;
  int tx = tid & 31;
  int ty = tid >> 5;
  int rowBase = bl * 64;

  float acc[8][CPT];
#pragma unroll
  for (int i = 0; i < 8; ++i)
#pragma unroll
    for (int j = 0; j < CPT; ++j) acc[i][j] = 0.f;

  for (int kc = 0; kc < K; kc += KC) {
    __syncthreads();
    {
      const float4* B4 = (const float4*)(Bc + (size_t)kc * NC);
      float4* Bs4 = (float4*)Bs;
#pragma unroll
      for (int i = tid; i < KC * NC / 4; i += 256) Bs4[i] = B4[i];
    }
    if constexpr (AHALF) {
      const __half* Ac = (const __half*)Av + (size_t)c * NN * K;
      int lr = tid >> 2;
      int lc = (tid & 3) * 8;
      int gr = rowBase + lr;
      uint4 v = make_uint4(0u, 0u, 0u, 0u);
      if (gr < NN) v = *(const uint4*)&Ac[(size_t)gr * K + kc + lc];
      const __half2* hp = (const __half2*)&v;
#pragma unroll
      for (int j = 0; j < 4; ++j) {
        float2 f = __half22float2(hp[j]);
        As[lr][lc + 2 * j]     = f.x;
        As[lr][lc + 2 * j + 1] = f.y;
      }
    } else {
      const float* Ac = (const float*)Av + (size_t)c * NN * K;
      int lr = tid >> 3;
      int lc = (tid & 7) * 4;
#pragma unroll
      for (int rr = 0; rr < 64; rr += 32) {
        int r = lr + rr;
        int gr = rowBase + r;
        float4 v = make_float4(0.f, 0.f, 0.f, 0.f);
        if (gr < NN) v = *(const float4*)&Ac[(size_t)gr * K + kc + lc];
        *(float4*)&As[r][lc] = v;
      }
    }
    __syncthreads();

#pragma unroll
    for (int kk = 0; kk < KC; kk += 4) {
      float4 av[8];
#pragma unroll
      for (int i = 0; i < 8; ++i) av[i] = *(const float4*)&As[ty * 8 + i][kk];
#pragma unroll
      for (int u = 0; u < 4; ++u) {
        int k = kk + u;
        if constexpr (CPT == 4) {
          float4 bv = *(const float4*)&Bs[k * NC + tx * 4];
#pragma unroll
          for (int i = 0; i < 8; ++i) {
            float a = ((const float*)&av[i])[u];
            acc[i][0] += a * bv.x;
            acc[i][1] += a * bv.y;
            acc[i][2] += a * bv.z;
            acc[i][3] += a * bv.w;
          }
        } else {
          float2 bv = *(const float2*)&Bs[k * NC + tx * 2];
#pragma unroll
          for (int i = 0; i < 8; ++i) {
            float a = ((const float*)&av[i])[u];
            acc[i][0] += a * bv.x;
            acc[i][1] += a * bv.y;
          }
        }
      }
    }
  }

#pragma unroll
  for (int i = 0; i < 8; ++i) {
    int gr = rowBase + ty * 8 + i;
    if (gr >= NN) continue;
    if constexpr (CPT == 4) {
      unsigned lo = pack2h(acc[i][0], acc[i][1]);
      unsigned hi = pack2h(acc[i][2], acc[i][3]);
      *(uint2*)&Cc[(size_t)gr * NC + tx * 4] = make_uint2(lo, hi);
    } else {
      *(unsigned*)&Cc[(size_t)gr * NC + tx * 2] = pack2h(acc[i][0], acc[i][1]);
    }
  }
}

// Fused: hist (atomic-bound) || gemm1 (VALU-bound) - fully independent.
__global__ __launch_bounds__(256) void fused_hist_gemm1_kernel(
    const float* __restrict__ x, const float* __restrict__ W1, __half* __restrict__ h1,
    const int* __restrict__ ei, const float* __restrict__ ew,
    unsigned* packed, int* __restrict__ pos) {
  int id = blockIdx.x;
  if (id & 1) {
    hist_body(id >> 1, HIST_BLOCKS, ei, ew, packed, pos);
  } else {
    int gid = id >> 1;
    if (gid < GEMM_BLOCKS) gemm_body<D_H, false>(gid, x, W1, h1);
  }
}

// ---------------------------------------------------------------------------
// agg1 body: F=128, one wave per node, fp16 gathers (half2/lane).
// Scalar edge bounds; 16B uint4 CSR loads; 32-bit gather offsets.
// out = relu(bias + dis^2*h[n] + sum norm*h[src]) -> fp16 (feeds gemm2).
// ---------------------------------------------------------------------------

__device__ inline void agg1_body(int bid, const __half2* __restrict__ h,
                                 const int* __restrict__ rowptr,
                                 const unsigned* __restrict__ csr,
                                 const float* __restrict__ dis,
                                 const float* __restrict__ bias,
                                 __half* __restrict__ out) {
  int c  = bid / BLK_AGG_REL;
  int bl = bid - c * BLK_AGG_REL;
  int node = bl * 4 + (threadIdx.x >> 6);
  int lane = threadIdx.x & 63;

  const __half2* hc = h + (size_t)c * (NN * 64);
  const unsigned* csrc = csr + (size_t)c * EE;
  int beg = __builtin_amdgcn_readfirstlane(rowptr[c * (NN + 1) + node]);
  int end = __builtin_amdgcn_readfirstlane(rowptr[c * (NN + 1) + node + 1]);

  float a0 = 0.f, a1 = 0.f;
#define AGG1_EDGE(ent)                                             \
  {                                                                \
    unsigned _e = (ent);                                           \
    unsigned _off = (_e & 0xffffu) * 64u + (unsigned)lane;         \
    float2 _v = __half22float2(hc[_off]);                          \
    float _nm = __half2float(__ushort_as_half((unsigned short)(_e >> 16))); \
    a0 += _nm * _v.x;                                              \
    a1 += _nm * _v.y;                                              \
  }
  int idx = beg;
  int hd = min(end, (beg + 3) & ~3);
  for (; idx < hd; ++idx) AGG1_EDGE(csrc[idx]);
  for (; idx + 4 <= end; idx += 4) {
    uint4 q = *(const uint4*)(csrc + idx);
    AGG1_EDGE(q.x);
    AGG1_EDGE(q.y);
    AGG1_EDGE(q.z);
    AGG1_EDGE(q.w);
  }
  for (; idx < end; ++idx) AGG1_EDGE(csrc[idx]);
#undef AGG1_EDGE

  float dn = dis[c * NN + node];
  float sn = dn * dn;                                 // self-loop norm
  float2 hv = __half22float2(hc[(unsigned)node * 64u + (unsigned)lane]);
  int f = lane * 2;
  a0 += sn * hv.x + bias[c * 128 + f];
  a1 += sn * hv.y + bias[c * 128 + f + 1];
  a0 = fmaxf(a0, 0.f);
  a1 = fmaxf(a1, 0.f);
  ((unsigned*)out)[((size_t)c * NN + node) * 64 + lane] = pack2h(a0, a1);
}

// agg2 body: F=64, one wave per node, half-wave edge split, shfl_xor(32).
// fp32 final output.
__device__ inline void agg2_body(int bid, const __half2* __restrict__ h,
                                 const int* __restrict__ rowptr,
                                 const unsigned* __restrict__ csr,
                                 const float* __restrict__ dis,
                                 const float* __restrict__ bias,
                                 float* __restrict__ out) {
  int c  = bid / BLK_AGG_REL;
  int bl = bid - c * BLK_AGG_REL;
  int node = bl * 4 + (threadIdx.x >> 6);
  int lane = threadIdx.x & 63;
  int hf = lane >> 5;
  int fl = lane & 31;

  const __half2* hc = h + (size_t)c * (NN * 32);
  const unsigned* csrc = csr + (size_t)c * EE;
  int beg = __builtin_amdgcn_readfirstlane(rowptr[c * (NN + 1) + node]);
  int end = __builtin_amdgcn_readfirstlane(rowptr[c * (NN + 1) + node + 1]);

  float a0 = 0.f, a1 = 0.f;
  int idx = beg + hf;
  for (; idx + 2 < end; idx += 4) {
    unsigned ea = csrc[idx], eb = csrc[idx + 2];
    float2 va = __half22float2(hc[(ea & 0xffffu) * 32u + (unsigned)fl]);
    float2 vb = __half22float2(hc[(eb & 0xffffu) * 32u + (unsigned)fl]);
    float na = __half2float(__ushort_as_half((unsigned short)(ea >> 16)));
    float nb = __half2float(__ushort_as_half((unsigned short)(eb >> 16)));
    a0 += na * va.x + nb * vb.x;
    a1 += na * va.y + nb * vb.y;
  }
  for (; idx < end; idx += 2) {
    unsigned e = csrc[idx];
    float2 v = __half22float2(hc[(e & 0xffffu) * 32u + (unsigned)fl]);
    float nm = __half2float(__ushort_as_half((unsigned short)(e >> 16)));
    a0 += nm * v.x;
    a1 += nm * v.y;
  }
  a0 += __shfl_xor(a0, 32, 64);
  a1 += __shfl_xor(a1, 32, 64);
  if (hf == 0) {
    float dn = dis[c * NN + node];
    float sn = dn * dn;
    float2 hv = __half22float2(hc[(unsigned)node * 32u + (unsigned)fl]);
    int f = fl * 2;
    a0 += sn * hv.x + bias[c * 64 + f];
    a1 += sn * hv.y + bias[c * 64 + f + 1];
    *(float2*)&out[((size_t)c * NN + node) * 64 + f] = make_float2(a0, a1);
  }
}

// ---------------------------------------------------------------------------
// Pipelined dispatch P(cc): agg1(cc) || fill(cc+1) || gemm2(cc-1) || agg2(cc-2)
// Roles interleaved 10:10:1:1 per 22-block group for co-residency.
// All roles touch disjoint relation slices -> no intra-dispatch races.
// ---------------------------------------------------------------------------

__global__ __launch_bounds__(256) void fused_pipe_kernel(
    int cc, const __half2* __restrict__ h1, const int* __restrict__ rowptr,
    const unsigned* __restrict__ csr, const float* __restrict__ dis,
    const float* __restrict__ b1, __half* __restrict__ agg1h,
    const float* __restrict__ W2, const float* __restrict__ b2,
    float* __restrict__ out, const int* __restrict__ ei,
    const float* __restrict__ ew, const int* __restrict__ pos) {
  int i = blockIdx.x;
  int grp = i / 22;
  int r = i - grp * 22;
  if (r < 10) {
    if (cc < C_REL)
      agg1_body(cc * BLK_AGG_REL + grp * 10 + r, h1, rowptr, csr, dis, b1, agg1h);
  } else if (r < 20) {
    if (cc >= 2)
      agg2_body((cc - 2) * BLK_AGG_REL + grp * 10 + (r - 10), h1, rowptr, csr, dis,
                b2, out);
  } else if (r == 20) {
    if (cc + 1 < C_REL)
      fill_rel_body(cc + 1, grp, FILLS_BLOCKS, ei, ew, dis, rowptr, pos,
                    (unsigned*)csr);
  } else {
    if (cc >= 1 && cc <= C_REL && grp < BLK_GEMM_REL)
      gemm_body<D_OUT, true>((cc - 1) * BLK_GEMM_REL + grp, agg1h, W2,
                             (__half*)h1);
  }
}

// ---------------------------------------------------------------------------
// Host launcher
// ---------------------------------------------------------------------------

extern "C" void kernel_launch(void* const* d_in, const int* in_sizes, int n_in,
                              void* d_out, int out_size, void* d_ws, size_t ws_size,
                              hipStream_t stream) {
  const float* x  = (const float*)d_in[0];   // [C][N][128]
  const int*   ei = (const int*)d_in[1];     // [C][2][E]
  const float* ew = (const float*)d_in[2];   // [C][E]
  const float* W1 = (const float*)d_in[3];   // [C][128][128]
  const float* b1 = (const float*)d_in[4];   // [C][128]
  const float* W2 = (const float*)d_in[5];   // [C][128][64]
  const float* b2 = (const float*)d_in[6];   // [C][64]
  float* out = (float*)d_out;                // [C][N][64]

  char* ws = (char*)d_ws;
  size_t off = 0;
  auto alloc = [&](size_t bytes) {
    size_t cur = off;
    off += (bytes + 255) & ~(size_t)255;
    return cur;
  };
  unsigned* packed = (unsigned*)(ws + alloc((size_t)CN * 4));
  float*    dis    = (float*)   (ws + alloc((size_t)CN * 4));
  int*      rowptr = (int*)     (ws + alloc((size_t)C_REL * (NN + 1) * 4));
  int*      bsum   = (int*)     (ws + alloc((size_t)C_REL * 256 * 4));
  unsigned* csr    = (unsigned*)(ws + alloc((size_t)CE * 4));
  __half*   h1     = (__half*)  (ws + alloc((size_t)CN * D_H * 2));   // h1 & h2 fp16
  __half*   agg1h  = (__half*)  (ws + alloc((size_t)CN * D_H * 2));   // relu out fp16
  int*      pos    = (int*)     (ws + alloc((size_t)CE * 4));
  // h2[c] = gemm2 output lives in h1 buffer at c*NN*64 halfs; always below the
  // h1[c'] regions (c'*NN*128) still being read by later agg1 passes. Verified
  // disjoint per pipeline stage.

  const int NB_CN = (CN + 255) / 256;

  init_kernel<<<NB_CN, 256, 0, stream>>>(packed);
  // hist (atomic-bound) overlapped with gemm1 (VALU-bound, independent).
  fused_hist_gemm1_kernel<<<FUSED_GRID, 256, 0, stream>>>(x, W1, h1, ei, ew, packed, pos);
  scan_a_kernel<<<C_REL * SCAN_B, 256, 0, stream>>>(packed, rowptr, bsum, dis);
  scan_c_kernel<<<C_REL * SCAN_B, 256, 0, stream>>>(rowptr, bsum);
  fill0_kernel<<<FILL0_BLOCKS, 256, 0, stream>>>(ei, ew, dis, rowptr, pos, csr);

  // Software pipeline: P(cc) = agg1(cc) || fill(cc+1) || gemm2(cc-1) || agg2(cc-2)
  for (int cc = 0; cc <= 6; ++cc) {
    fused_pipe_kernel<<<PIPE_GRID, 256, 0, stream>>>(
        cc, (const __half2*)h1, rowptr, csr, dis, b1, agg1h, W2, b2, out, ei, ew, pos);
  }
}